// Round 1
// baseline (319.488 us; speedup 1.0000x reference)
//
#include <hip/hip_runtime.h>
#include <hip/hip_bf16.h>
#include <math.h>

#define EMBED 1024
#define HDIM  64
#define BATCH 4
#define SEQ   2048

typedef __attribute__((ext_vector_type(8))) short short8;
typedef __attribute__((ext_vector_type(4))) float f32x4;
typedef unsigned int u32;
typedef unsigned short u16;

static __device__ __forceinline__ u16 f2bf(float f) {
    union { float f; u32 u; } v; v.f = f;
    u32 r = v.u + 0x7fffu + ((v.u >> 16) & 1u);  // round-to-nearest-even
    return (u16)(r >> 16);
}

// async global->LDS, 16B per lane. LDS dest must equal uniform_base + lane*16.
static __device__ __forceinline__ void gload_lds16(const u16* g, u16* l) {
    __builtin_amdgcn_global_load_lds(
        (const __attribute__((address_space(1))) u32*)g,
        (__attribute__((address_space(3))) u32*)l, 16, 0, 0);
}

// ---------------------------------------------------------------------------
// K1: Q = h*Wq + bq, K = h*Wk + bk  (fp32 accumulate, bf16 out)
// grid 256 blocks x 256 thr; block = 32 s-rows. threads: c=d-col(64) x half(q/k) x rowgroup(2)
// ---------------------------------------------------------------------------
__global__ __launch_bounds__(256) void proj_kernel(
    const float* __restrict__ h, const float* __restrict__ Wq, const float* __restrict__ bq,
    const float* __restrict__ Wk, const float* __restrict__ bk,
    u16* __restrict__ Qbf, u16* __restrict__ Kbf)
{
    __shared__ float hs[32][128];
    int row0 = blockIdx.x * 32;
    int t = threadIdx.x;
    int c    = t & 63;
    int half = (t >> 6) & 1;
    int rg   = t >> 7;
    const float* W    = half ? Wk : Wq;
    const float* bias = half ? bk : bq;
    float acc[16];
#pragma unroll
    for (int i = 0; i < 16; i++) acc[i] = 0.f;
    for (int ec = 0; ec < EMBED; ec += 128) {
        __syncthreads();
        for (int i = t; i < 32 * 128; i += 256) {
            int r = i >> 7, cc = i & 127;
            hs[r][cc] = h[(size_t)(row0 + r) * EMBED + ec + cc];
        }
        __syncthreads();
        for (int i = 0; i < 128; i++) {
            float w = W[(size_t)(ec + i) * HDIM + c];
#pragma unroll
            for (int r = 0; r < 16; r++) acc[r] += hs[rg * 16 + r][i] * w;
        }
    }
    float bb = bias[c];
    u16* outp = half ? Kbf : Qbf;
    for (int r = 0; r < 16; r++)
        outp[(size_t)(row0 + rg * 16 + r) * HDIM + c] = f2bf(acc[r] + bb);
}

// ---------------------------------------------------------------------------
// K2: hT[b][e][s] = bf16(h[b][s][e])  — 64x64 tiles via LDS
// ---------------------------------------------------------------------------
__global__ __launch_bounds__(256) void transpose_kernel(
    const float* __restrict__ h, u16* __restrict__ hT)
{
    __shared__ float tile[64][65];
    int b  = blockIdx.z;
    int s0 = blockIdx.x * 64, e0 = blockIdx.y * 64;
    int t = threadIdx.x, c = t & 63, r4 = t >> 6;
    const float* hb = h + (size_t)b * SEQ * EMBED;
    for (int r = r4; r < 64; r += 4)
        tile[r][c] = hb[(size_t)(s0 + r) * EMBED + e0 + c];
    __syncthreads();
    u16* hTb = hT + (size_t)b * EMBED * SEQ;
    for (int er = r4; er < 64; er += 4)
        hTb[(size_t)(e0 + er) * SEQ + s0 + c] = f2bf(tile[c][er]);
}

// ---------------------------------------------------------------------------
// K3: column softmax stats. scores[q][k], softmax over q => per-(b,k) m,l.
// 1 wave per 16 k-columns; online max/sumexp over 128 q-tiles of 16.
// MFMA C-layout: col(k)=lane&15, row(q)=quad*4+reg  => reduce over regs + xor16/32.
// ---------------------------------------------------------------------------
__global__ __launch_bounds__(64) void stats_kernel(
    const u16* __restrict__ Qbf, const u16* __restrict__ Kbf,
    float* __restrict__ mArr, float* __restrict__ lArr)
{
    int b = blockIdx.y;
    int k0 = blockIdx.x * 16;
    int lane = threadIdx.x, l15 = lane & 15, quad = lane >> 4;
    const u16* Qb = Qbf + (size_t)b * SEQ * HDIM;
    const u16* Kb = Kbf + (size_t)b * SEQ * HDIM;
    short8 kf0 = *(const short8*)(Kb + (size_t)(k0 + l15) * HDIM + quad * 8);
    short8 kf1 = *(const short8*)(Kb + (size_t)(k0 + l15) * HDIM + 32 + quad * 8);
    float m_run = -1e30f, l_run = 0.f;
    for (int q0 = 0; q0 < SEQ; q0 += 16) {
        short8 qf0 = *(const short8*)(Qb + (size_t)(q0 + l15) * HDIM + quad * 8);
        short8 qf1 = *(const short8*)(Qb + (size_t)(q0 + l15) * HDIM + 32 + quad * 8);
        f32x4 acc = {0.f, 0.f, 0.f, 0.f};
        acc = __builtin_amdgcn_mfma_f32_16x16x32_bf16(qf0, kf0, acc, 0, 0, 0);
        acc = __builtin_amdgcn_mfma_f32_16x16x32_bf16(qf1, kf1, acc, 0, 0, 0);
        float s0 = acc[0] * 0.125f, s1 = acc[1] * 0.125f;
        float s2 = acc[2] * 0.125f, s3 = acc[3] * 0.125f;
        float tm = fmaxf(fmaxf(s0, s1), fmaxf(s2, s3));
        tm = fmaxf(tm, __shfl_xor(tm, 16, 64));
        tm = fmaxf(tm, __shfl_xor(tm, 32, 64));
        float mn = fmaxf(m_run, tm);
        float p = __expf(s0 - mn) + __expf(s1 - mn) + __expf(s2 - mn) + __expf(s3 - mn);
        p += __shfl_xor(p, 16, 64);
        p += __shfl_xor(p, 32, 64);
        l_run = l_run * __expf(m_run - mn) + p;
        m_run = mn;
    }
    if (quad == 0) {
        mArr[b * SEQ + k0 + l15] = m_run;
        lArr[b * SEQ + k0 + l15] = l_run;
    }
}

// ---------------------------------------------------------------------------
// K4: Wmat[b][q][k] = bf16( exp(s - m[k]) / l[k] )  — recompute QK^T via MFMA
// grid (S/64, S/64, B); 4 waves, wave w = q-subtile w*16, loops 4 k-subtiles.
// ---------------------------------------------------------------------------
__global__ __launch_bounds__(256) void weights_kernel(
    const u16* __restrict__ Qbf, const u16* __restrict__ Kbf,
    const float* __restrict__ mArr, const float* __restrict__ lArr,
    u16* __restrict__ Wmat)
{
    int b = blockIdx.z;
    int q0 = blockIdx.x * 64, k0 = blockIdx.y * 64;
    int t = threadIdx.x, lane = t & 63, w = t >> 6;
    int l15 = lane & 15, quad = lane >> 4;
    const u16* Qb = Qbf + (size_t)b * SEQ * HDIM;
    const u16* Kb = Kbf + (size_t)b * SEQ * HDIM;
    int q = q0 + w * 16;
    short8 qf0 = *(const short8*)(Qb + (size_t)(q + l15) * HDIM + quad * 8);
    short8 qf1 = *(const short8*)(Qb + (size_t)(q + l15) * HDIM + 32 + quad * 8);
    u16* Wb = Wmat + (size_t)b * SEQ * SEQ;
#pragma unroll
    for (int kt = 0; kt < 4; kt++) {
        int k = k0 + kt * 16;
        short8 kf0 = *(const short8*)(Kb + (size_t)(k + l15) * HDIM + quad * 8);
        short8 kf1 = *(const short8*)(Kb + (size_t)(k + l15) * HDIM + 32 + quad * 8);
        f32x4 acc = {0.f, 0.f, 0.f, 0.f};
        acc = __builtin_amdgcn_mfma_f32_16x16x32_bf16(qf0, kf0, acc, 0, 0, 0);
        acc = __builtin_amdgcn_mfma_f32_16x16x32_bf16(qf1, kf1, acc, 0, 0, 0);
        float mv  = mArr[b * SEQ + k + l15];
        float inv = 1.0f / lArr[b * SEQ + k + l15];
#pragma unroll
        for (int r = 0; r < 4; r++) {
            float s  = acc[r] * 0.125f;
            float wv = __expf(s - mv) * inv;
            Wb[(size_t)(q + quad * 4 + r) * SEQ + k + l15] = f2bf(wv);
        }
    }
}

// ---------------------------------------------------------------------------
// K5: out[b][q][e] = sum_k Wmat[b][q][k] * h[b][k][e]   (B operand from hT[e][k])
// 128x128 tile, BK=32, global_load_lds width-16 staging, 4 waves in 2x2.
// ---------------------------------------------------------------------------
__global__ __launch_bounds__(256) void out_gemm_kernel(
    const u16* __restrict__ Wmat, const u16* __restrict__ hT, float* __restrict__ out)
{
    __shared__ u16 As[128 * 32];  // [q][k], 64B rows
    __shared__ u16 Bs[128 * 32];  // [e][k], 64B rows
    int b = blockIdx.z;
    int q0 = blockIdx.x * 128, e0 = blockIdx.y * 128;
    int t = threadIdx.x, lane = t & 63, w = t >> 6;
    int l15 = lane & 15, quad = lane >> 4;
    const u16* Wb  = Wmat + (size_t)b * SEQ * SEQ;
    const u16* hTb = hT + (size_t)b * EMBED * SEQ;
    int wq = (w & 1) * 64, we = (w >> 1) * 64;

    f32x4 acc[4][4];
#pragma unroll
    for (int qi = 0; qi < 4; qi++)
#pragma unroll
        for (int ei = 0; ei < 4; ei++) acc[qi][ei] = (f32x4){0.f, 0.f, 0.f, 0.f};

    int srow = (lane >> 2);        // 0..15 within a 16-row group
    int scol = (lane & 3) * 8;     // 0,8,16,24

    for (int k0 = 0; k0 < SEQ; k0 += 32) {
        __syncthreads();
#pragma unroll
        for (int ld = 0; ld < 2; ld++) {
            int row = w * 32 + ld * 16 + srow;
            gload_lds16(Wb  + (size_t)(q0 + row) * SEQ + k0 + scol, As + row * 32 + scol);
            gload_lds16(hTb + (size_t)(e0 + row) * SEQ + k0 + scol, Bs + row * 32 + scol);
        }
        __syncthreads();  // drains vmcnt (global_load_lds) before frag reads

        short8 af[4], bfr[4];
#pragma unroll
        for (int i = 0; i < 4; i++) {
            af[i]  = *(const short8*)(As + (wq + i * 16 + l15) * 32 + quad * 8);
            bfr[i] = *(const short8*)(Bs + (we + i * 16 + l15) * 32 + quad * 8);
        }
#pragma unroll
        for (int qi = 0; qi < 4; qi++)
#pragma unroll
            for (int ei = 0; ei < 4; ei++)
                acc[qi][ei] = __builtin_amdgcn_mfma_f32_16x16x32_bf16(
                    af[qi], bfr[ei], acc[qi][ei], 0, 0, 0);
    }

    float* outb = out + (size_t)b * SEQ * EMBED;
#pragma unroll
    for (int qi = 0; qi < 4; qi++)
#pragma unroll
        for (int ei = 0; ei < 4; ei++)
#pragma unroll
            for (int r = 0; r < 4; r++)
                outb[(size_t)(q0 + wq + qi * 16 + quad * 4 + r) * EMBED
                     + e0 + we + ei * 16 + l15] = acc[qi][ei][r];
}

// ---------------------------------------------------------------------------
extern "C" void kernel_launch(void* const* d_in, const int* in_sizes, int n_in,
                              void* d_out, int out_size, void* d_ws, size_t ws_size,
                              hipStream_t stream) {
    (void)in_sizes; (void)n_in; (void)out_size; (void)ws_size;
    const float* h  = (const float*)d_in[0];
    const float* Wq = (const float*)d_in[1];
    const float* bq = (const float*)d_in[2];
    const float* Wk = (const float*)d_in[3];
    const float* bk = (const float*)d_in[4];
    // d_in[5], d_in[6] (Wv, bv) are dead in the reference.
    float* out = (float*)d_out;

    char* ws = (char*)d_ws;
    u16*   Qbf  = (u16*)(ws);                               // 1 MB
    u16*   Kbf  = (u16*)(ws + (1ull << 20));                // 1 MB
    u16*   hT   = (u16*)(ws + (2ull << 20));                // 16 MB
    float* mArr = (float*)(ws + (18ull << 20));             // 32 KB
    float* lArr = (float*)(ws + (18ull << 20) + (64 << 10));// 32 KB
    u16*   Wmat = (u16*)(ws + (19ull << 20));               // 33.5 MB  (total ~52.6 MB)

    hipLaunchKernelGGL(proj_kernel, dim3(256), dim3(256), 0, stream,
                       h, Wq, bq, Wk, bk, Qbf, Kbf);
    hipLaunchKernelGGL(transpose_kernel, dim3(32, 16, 4), dim3(256), 0, stream, h, hT);
    hipLaunchKernelGGL(stats_kernel, dim3(128, 4), dim3(64), 0, stream,
                       Qbf, Kbf, mArr, lArr);
    hipLaunchKernelGGL(weights_kernel, dim3(32, 32, 4), dim3(256), 0, stream,
                       Qbf, Kbf, mArr, lArr, Wmat);
    hipLaunchKernelGGL(out_gemm_kernel, dim3(16, 8, 4), dim3(256), 0, stream,
                       Wmat, hT, out);
}

// Round 2
// 242.723 us; speedup vs baseline: 1.3163x; 1.3163x over previous
//
#include <hip/hip_runtime.h>
#include <hip/hip_bf16.h>
#include <math.h>

#define EMBED 1024
#define HDIM  64
#define BATCH 4
#define SEQ   2048

typedef __attribute__((ext_vector_type(8))) short short8;
typedef __attribute__((ext_vector_type(4))) float f32x4;
typedef unsigned int u32;
typedef unsigned short u16;

static __device__ __forceinline__ u16 f2bf(float f) {
    union { float f; u32 u; } v; v.f = f;
    u32 r = v.u + 0x7fffu + ((v.u >> 16) & 1u);  // round-to-nearest-even
    return (u16)(r >> 16);
}

// async global->LDS, 16B per lane. LDS dest must equal uniform_base + lane*16.
static __device__ __forceinline__ void gload_lds16(const u16* g, u16* l) {
    __builtin_amdgcn_global_load_lds(
        (const __attribute__((address_space(1))) u32*)g,
        (__attribute__((address_space(3))) u32*)l, 16, 0, 0);
}

// ---------------------------------------------------------------------------
// K0: WqT[d][e] = bf16(Wq[e][d]), WkT likewise. grid (16,2) x 256.
// ---------------------------------------------------------------------------
__global__ __launch_bounds__(256) void wt_kernel(
    const float* __restrict__ Wq, const float* __restrict__ Wk,
    u16* __restrict__ WqT, u16* __restrict__ WkT)
{
    __shared__ float tile[64][65];
    const float* W = blockIdx.y ? Wk : Wq;
    u16* WT = blockIdx.y ? WkT : WqT;
    int e0 = blockIdx.x * 64;
    int t = threadIdx.x, c = t & 63, r4 = t >> 6;
    for (int r = r4; r < 64; r += 4)
        tile[r][c] = W[(size_t)(e0 + r) * HDIM + c];   // tile[e-e0][d]
    __syncthreads();
    for (int d = r4; d < 64; d += 4)
        WT[(size_t)d * EMBED + e0 + c] = f2bf(tile[c][d]);
}

// ---------------------------------------------------------------------------
// K1: fused. Per block: 32 s-rows of one batch. Single pass over h:
//   - stage h tile (32s x 32e) in LDS as bf16
//   - MFMA: Q += A*WqT, K += A*WkT  (A-frags from LDS, B-frags from L2)
//   - write transposed slice hT[e][s]
// grid 256 (= B * S/32), 256 thr (4 waves; wave w owns d-cols w*16..w*16+15).
// ---------------------------------------------------------------------------
__global__ __launch_bounds__(256) void fused_proj_kernel(
    const float* __restrict__ h, const u16* __restrict__ WqT, const u16* __restrict__ WkT,
    const float* __restrict__ bq, const float* __restrict__ bk,
    u16* __restrict__ Qbf, u16* __restrict__ Kbf, u16* __restrict__ hT)
{
    __shared__ u16 hs[32][40];   // +8 pad: 80B rows (16B aligned), spreads banks
    int b = blockIdx.x >> 6, s0 = (blockIdx.x & 63) * 32;
    int t = threadIdx.x, lane = t & 63, w = t >> 6;
    int l15 = lane & 15, quad = lane >> 4;
    const float* hb = h + ((size_t)b * SEQ + s0) * EMBED;
    u16* hTb = hT + (size_t)b * EMBED * SEQ;

    int lrow = t >> 3, lcol = (t & 7) * 4;   // ingest: 32 rows x 8 float4
    f32x4 pre = *(const f32x4*)(hb + (size_t)lrow * EMBED + lcol);

    f32x4 accQ[2], accK[2];
    accQ[0] = accQ[1] = accK[0] = accK[1] = (f32x4){0.f, 0.f, 0.f, 0.f};

    const u16* WqRow = WqT + (size_t)(w * 16 + l15) * EMBED;
    const u16* WkRow = WkT + (size_t)(w * 16 + l15) * EMBED;

    for (int ec = 0; ec < EMBED; ec += 32) {
        // stage prefetched chunk into LDS (bf16)
        uint2 pk;
        pk.x = (u32)f2bf(pre[0]) | ((u32)f2bf(pre[1]) << 16);
        pk.y = (u32)f2bf(pre[2]) | ((u32)f2bf(pre[3]) << 16);
        *(uint2*)&hs[lrow][lcol] = pk;
        __syncthreads();

        // prefetch next chunk (overlaps MFMA + LDS work below)
        f32x4 nxt = pre;
        if (ec + 32 < EMBED)
            nxt = *(const f32x4*)(hb + (size_t)lrow * EMBED + ec + 32 + lcol);

        // B fragments (WqT/WkT are 128KB each, L2-resident)
        short8 bqf = *(const short8*)(WqRow + ec + quad * 8);
        short8 bkf = *(const short8*)(WkRow + ec + quad * 8);
        // A fragments from LDS
        short8 a0 = *(const short8*)&hs[l15][quad * 8];
        short8 a1 = *(const short8*)&hs[16 + l15][quad * 8];
        accQ[0] = __builtin_amdgcn_mfma_f32_16x16x32_bf16(a0, bqf, accQ[0], 0, 0, 0);
        accQ[1] = __builtin_amdgcn_mfma_f32_16x16x32_bf16(a1, bqf, accQ[1], 0, 0, 0);
        accK[0] = __builtin_amdgcn_mfma_f32_16x16x32_bf16(a0, bkf, accK[0], 0, 0, 0);
        accK[1] = __builtin_amdgcn_mfma_f32_16x16x32_bf16(a1, bkf, accK[1], 0, 0, 0);

        // transposed write: e-row = ec + lrow, s-cols s0 + lcol .. +3
        {
            u16 v0 = hs[lcol    ][lrow];
            u16 v1 = hs[lcol + 1][lrow];
            u16 v2 = hs[lcol + 2][lrow];
            u16 v3 = hs[lcol + 3][lrow];
            uint2 pk2;
            pk2.x = (u32)v0 | ((u32)v1 << 16);
            pk2.y = (u32)v2 | ((u32)v3 << 16);
            *(uint2*)(hTb + (size_t)(ec + lrow) * SEQ + s0 + lcol) = pk2;
        }
        __syncthreads();   // all reads done before next iteration overwrites
        pre = nxt;
    }

    // epilogue: C layout col=l15 (d), row=quad*4+r (s within m-tile)
    float bqv = bq[w * 16 + l15], bkv = bk[w * 16 + l15];
#pragma unroll
    for (int mt = 0; mt < 2; mt++)
#pragma unroll
        for (int r = 0; r < 4; r++) {
            size_t srow = (size_t)b * SEQ + s0 + mt * 16 + quad * 4 + r;
            Qbf[srow * HDIM + w * 16 + l15] = f2bf(accQ[mt][r] + bqv);
            Kbf[srow * HDIM + w * 16 + l15] = f2bf(accK[mt][r] + bkv);
        }
}

// ---------------------------------------------------------------------------
// K3: column softmax stats. scores[q][k], softmax over q => per-(b,k) m,l.
// 1 wave per 16 k-columns; online max/sumexp over 128 q-tiles of 16.
// MFMA C-layout: col(k)=lane&15, row(q)=quad*4+reg  => reduce over regs + xor16/32.
// ---------------------------------------------------------------------------
__global__ __launch_bounds__(64) void stats_kernel(
    const u16* __restrict__ Qbf, const u16* __restrict__ Kbf,
    float* __restrict__ mArr, float* __restrict__ lArr)
{
    int b = blockIdx.y;
    int k0 = blockIdx.x * 16;
    int lane = threadIdx.x, l15 = lane & 15, quad = lane >> 4;
    const u16* Qb = Qbf + (size_t)b * SEQ * HDIM;
    const u16* Kb = Kbf + (size_t)b * SEQ * HDIM;
    short8 kf0 = *(const short8*)(Kb + (size_t)(k0 + l15) * HDIM + quad * 8);
    short8 kf1 = *(const short8*)(Kb + (size_t)(k0 + l15) * HDIM + 32 + quad * 8);
    float m_run = -1e30f, l_run = 0.f;
    for (int q0 = 0; q0 < SEQ; q0 += 16) {
        short8 qf0 = *(const short8*)(Qb + (size_t)(q0 + l15) * HDIM + quad * 8);
        short8 qf1 = *(const short8*)(Qb + (size_t)(q0 + l15) * HDIM + 32 + quad * 8);
        f32x4 acc = {0.f, 0.f, 0.f, 0.f};
        acc = __builtin_amdgcn_mfma_f32_16x16x32_bf16(qf0, kf0, acc, 0, 0, 0);
        acc = __builtin_amdgcn_mfma_f32_16x16x32_bf16(qf1, kf1, acc, 0, 0, 0);
        float s0 = acc[0] * 0.125f, s1 = acc[1] * 0.125f;
        float s2 = acc[2] * 0.125f, s3 = acc[3] * 0.125f;
        float tm = fmaxf(fmaxf(s0, s1), fmaxf(s2, s3));
        tm = fmaxf(tm, __shfl_xor(tm, 16, 64));
        tm = fmaxf(tm, __shfl_xor(tm, 32, 64));
        float mn = fmaxf(m_run, tm);
        float p = __expf(s0 - mn) + __expf(s1 - mn) + __expf(s2 - mn) + __expf(s3 - mn);
        p += __shfl_xor(p, 16, 64);
        p += __shfl_xor(p, 32, 64);
        l_run = l_run * __expf(m_run - mn) + p;
        m_run = mn;
    }
    if (quad == 0) {
        mArr[b * SEQ + k0 + l15] = m_run;
        lArr[b * SEQ + k0 + l15] = l_run;
    }
}

// ---------------------------------------------------------------------------
// K4: Wmat[b][q][k] = bf16( exp(s - m[k]) / l[k] )  — recompute QK^T via MFMA
// grid (S/64, S/64, B); 4 waves, wave w = q-subtile w*16, loops 4 k-subtiles.
// ---------------------------------------------------------------------------
__global__ __launch_bounds__(256) void weights_kernel(
    const u16* __restrict__ Qbf, const u16* __restrict__ Kbf,
    const float* __restrict__ mArr, const float* __restrict__ lArr,
    u16* __restrict__ Wmat)
{
    int b = blockIdx.z;
    int q0 = blockIdx.x * 64, k0 = blockIdx.y * 64;
    int t = threadIdx.x, lane = t & 63, w = t >> 6;
    int l15 = lane & 15, quad = lane >> 4;
    const u16* Qb = Qbf + (size_t)b * SEQ * HDIM;
    const u16* Kb = Kbf + (size_t)b * SEQ * HDIM;
    int q = q0 + w * 16;
    short8 qf0 = *(const short8*)(Qb + (size_t)(q + l15) * HDIM + quad * 8);
    short8 qf1 = *(const short8*)(Qb + (size_t)(q + l15) * HDIM + 32 + quad * 8);
    u16* Wb = Wmat + (size_t)b * SEQ * SEQ;
#pragma unroll
    for (int kt = 0; kt < 4; kt++) {
        int k = k0 + kt * 16;
        short8 kf0 = *(const short8*)(Kb + (size_t)(k + l15) * HDIM + quad * 8);
        short8 kf1 = *(const short8*)(Kb + (size_t)(k + l15) * HDIM + 32 + quad * 8);
        f32x4 acc = {0.f, 0.f, 0.f, 0.f};
        acc = __builtin_amdgcn_mfma_f32_16x16x32_bf16(qf0, kf0, acc, 0, 0, 0);
        acc = __builtin_amdgcn_mfma_f32_16x16x32_bf16(qf1, kf1, acc, 0, 0, 0);
        float mv  = mArr[b * SEQ + k + l15];
        float inv = 1.0f / lArr[b * SEQ + k + l15];
#pragma unroll
        for (int r = 0; r < 4; r++) {
            float s  = acc[r] * 0.125f;
            float wv = __expf(s - mv) * inv;
            Wb[(size_t)(q + quad * 4 + r) * SEQ + k + l15] = f2bf(wv);
        }
    }
}

// ---------------------------------------------------------------------------
// K5: out[b][q][e] = sum_k Wmat[b][q][k] * h[b][k][e]   (B operand from hT[e][k])
// 128x128 tile, BK=32, global_load_lds width-16 staging, 4 waves in 2x2.
// ---------------------------------------------------------------------------
__global__ __launch_bounds__(256) void out_gemm_kernel(
    const u16* __restrict__ Wmat, const u16* __restrict__ hT, float* __restrict__ out)
{
    __shared__ u16 As[128 * 32];  // [q][k], 64B rows
    __shared__ u16 Bs[128 * 32];  // [e][k], 64B rows
    int b = blockIdx.z;
    int q0 = blockIdx.x * 128, e0 = blockIdx.y * 128;
    int t = threadIdx.x, lane = t & 63, w = t >> 6;
    int l15 = lane & 15, quad = lane >> 4;
    const u16* Wb  = Wmat + (size_t)b * SEQ * SEQ;
    const u16* hTb = hT + (size_t)b * EMBED * SEQ;
    int wq = (w & 1) * 64, we = (w >> 1) * 64;

    f32x4 acc[4][4];
#pragma unroll
    for (int qi = 0; qi < 4; qi++)
#pragma unroll
        for (int ei = 0; ei < 4; ei++) acc[qi][ei] = (f32x4){0.f, 0.f, 0.f, 0.f};

    int srow = (lane >> 2);        // 0..15 within a 16-row group
    int scol = (lane & 3) * 8;     // 0,8,16,24

    for (int k0 = 0; k0 < SEQ; k0 += 32) {
        __syncthreads();
#pragma unroll
        for (int ld = 0; ld < 2; ld++) {
            int row = w * 32 + ld * 16 + srow;
            gload_lds16(Wb  + (size_t)(q0 + row) * SEQ + k0 + scol, As + row * 32 + scol);
            gload_lds16(hTb + (size_t)(e0 + row) * SEQ + k0 + scol, Bs + row * 32 + scol);
        }
        __syncthreads();  // drains vmcnt (global_load_lds) before frag reads

        short8 af[4], bfr[4];
#pragma unroll
        for (int i = 0; i < 4; i++) {
            af[i]  = *(const short8*)(As + (wq + i * 16 + l15) * 32 + quad * 8);
            bfr[i] = *(const short8*)(Bs + (we + i * 16 + l15) * 32 + quad * 8);
        }
#pragma unroll
        for (int qi = 0; qi < 4; qi++)
#pragma unroll
            for (int ei = 0; ei < 4; ei++)
                acc[qi][ei] = __builtin_amdgcn_mfma_f32_16x16x32_bf16(
                    af[qi], bfr[ei], acc[qi][ei], 0, 0, 0);
    }

    float* outb = out + (size_t)b * SEQ * EMBED;
#pragma unroll
    for (int qi = 0; qi < 4; qi++)
#pragma unroll
        for (int ei = 0; ei < 4; ei++)
#pragma unroll
            for (int r = 0; r < 4; r++)
                outb[(size_t)(q0 + wq + qi * 16 + quad * 4 + r) * EMBED
                     + e0 + we + ei * 16 + l15] = acc[qi][ei][r];
}

// ---------------------------------------------------------------------------
extern "C" void kernel_launch(void* const* d_in, const int* in_sizes, int n_in,
                              void* d_out, int out_size, void* d_ws, size_t ws_size,
                              hipStream_t stream) {
    (void)in_sizes; (void)n_in; (void)out_size; (void)ws_size;
    const float* h  = (const float*)d_in[0];
    const float* Wq = (const float*)d_in[1];
    const float* bq = (const float*)d_in[2];
    const float* Wk = (const float*)d_in[3];
    const float* bk = (const float*)d_in[4];
    // d_in[5], d_in[6] (Wv, bv) are dead in the reference.
    float* out = (float*)d_out;

    char* ws = (char*)d_ws;
    u16*   Qbf  = (u16*)(ws);                                  // 1 MB
    u16*   Kbf  = (u16*)(ws + (1ull << 20));                   // 1 MB
    u16*   hT   = (u16*)(ws + (2ull << 20));                   // 16 MB
    float* mArr = (float*)(ws + (18ull << 20));                // 32 KB
    float* lArr = (float*)(ws + (18ull << 20) + (64ull << 10));// 32 KB
    u16*   WqT  = (u16*)(ws + (18ull << 20) + (128ull << 10)); // 128 KB
    u16*   WkT  = (u16*)(ws + (18ull << 20) + (256ull << 10)); // 128 KB
    u16*   Wmat = (u16*)(ws + (19ull << 20));                  // 32 MB (total ~51 MB)

    hipLaunchKernelGGL(wt_kernel, dim3(16, 2), dim3(256), 0, stream, Wq, Wk, WqT, WkT);
    hipLaunchKernelGGL(fused_proj_kernel, dim3(256), dim3(256), 0, stream,
                       h, WqT, WkT, bq, bk, Qbf, Kbf, hT);
    hipLaunchKernelGGL(stats_kernel, dim3(128, 4), dim3(64), 0, stream,
                       Qbf, Kbf, mArr, lArr);
    hipLaunchKernelGGL(weights_kernel, dim3(32, 32, 4), dim3(256), 0, stream,
                       Qbf, Kbf, mArr, lArr, Wmat);
    hipLaunchKernelGGL(out_gemm_kernel, dim3(16, 8, 4), dim3(256), 0, stream,
                       Wmat, hT, out);
}

// Round 3
// 214.412 us; speedup vs baseline: 1.4901x; 1.1320x over previous
//
#include <hip/hip_runtime.h>
#include <hip/hip_bf16.h>
#include <math.h>

#define EMBED 1024
#define HDIM  64
#define BATCH 4
#define SEQ   2048

typedef __attribute__((ext_vector_type(8))) short short8;
typedef __attribute__((ext_vector_type(4))) float f32x4;
typedef unsigned int u32;
typedef unsigned short u16;

static __device__ __forceinline__ u16 f2bf(float f) {
    union { float f; u32 u; } v; v.f = f;
    u32 r = v.u + 0x7fffu + ((v.u >> 16) & 1u);  // round-to-nearest-even
    return (u16)(r >> 16);
}

// async global->LDS, 16B per lane. LDS dest must equal uniform_base + lane*16.
static __device__ __forceinline__ void gload_lds16(const u16* g, u16* l) {
    __builtin_amdgcn_global_load_lds(
        (const __attribute__((address_space(1))) u32*)g,
        (__attribute__((address_space(3))) u32*)l, 16, 0, 0);
}

// ---------------------------------------------------------------------------
// K0: WqT[d][e] = bf16(Wq[e][d]), WkT likewise. grid (16,2) x 256.
// ---------------------------------------------------------------------------
__global__ __launch_bounds__(256) void wt_kernel(
    const float* __restrict__ Wq, const float* __restrict__ Wk,
    u16* __restrict__ WqT, u16* __restrict__ WkT)
{
    __shared__ float tile[64][65];
    const float* W = blockIdx.y ? Wk : Wq;
    u16* WT = blockIdx.y ? WkT : WqT;
    int e0 = blockIdx.x * 64;
    int t = threadIdx.x, c = t & 63, r4 = t >> 6;
    for (int r = r4; r < 64; r += 4)
        tile[r][c] = W[(size_t)(e0 + r) * HDIM + c];   // tile[e-e0][d]
    __syncthreads();
    for (int d = r4; d < 64; d += 4)
        WT[(size_t)d * EMBED + e0 + c] = f2bf(tile[c][d]);
}

// ---------------------------------------------------------------------------
// K1: proj. Q = 0.125*(h*Wq + bq), K = h*Wk + bk   (bf16 out, scale folded in Q)
// grid 512 (B * S/16), 256 thr. Block = 16 s-rows. Wave w: proj=w>>1, n-half=(w&1)*32.
// LDS double-buffered 16x64 bf16 h-tile, stride 72 (conflict-free frag reads).
// ---------------------------------------------------------------------------
__global__ __launch_bounds__(256) void proj_kernel(
    const float* __restrict__ h, const u16* __restrict__ WqT, const u16* __restrict__ WkT,
    const float* __restrict__ bq, const float* __restrict__ bk,
    u16* __restrict__ Qbf, u16* __restrict__ Kbf)
{
    __shared__ u16 hs[2][16][72];
    int b = blockIdx.x >> 7, s0 = (blockIdx.x & 127) * 16;
    int t = threadIdx.x, lane = t & 63, w = t >> 6;
    int l15 = lane & 15, quad = lane >> 4;
    int pj = w >> 1, nh = (w & 1) * 32;
    const float* hb = h + ((size_t)b * SEQ + s0) * EMBED;
    const u16* Wp = pj ? WkT : WqT;
    int r = t >> 4, c4 = (t & 15) * 4;

    f32x4 pre = *(const f32x4*)(hb + (size_t)r * EMBED + c4);
    f32x4 acc[2];
    acc[0] = acc[1] = (f32x4){0.f, 0.f, 0.f, 0.f};

    const u16* Wrow0 = Wp + (size_t)(nh + l15) * EMBED;
    const u16* Wrow1 = Wp + (size_t)(nh + 16 + l15) * EMBED;

    for (int it = 0; it < 16; ++it) {
        int ec = it * 64, buf = it & 1;
        uint2 pk;
        pk.x = (u32)f2bf(pre[0]) | ((u32)f2bf(pre[1]) << 16);
        pk.y = (u32)f2bf(pre[2]) | ((u32)f2bf(pre[3]) << 16);
        *(uint2*)&hs[buf][r][c4] = pk;
        __syncthreads();
        if (it + 1 < 16)
            pre = *(const f32x4*)(hb + (size_t)r * EMBED + ec + 64 + c4);
        short8 bf00 = *(const short8*)(Wrow0 + ec + quad * 8);
        short8 bf01 = *(const short8*)(Wrow0 + ec + 32 + quad * 8);
        short8 bf10 = *(const short8*)(Wrow1 + ec + quad * 8);
        short8 bf11 = *(const short8*)(Wrow1 + ec + 32 + quad * 8);
        short8 a0 = *(const short8*)&hs[buf][l15][quad * 8];
        short8 a1 = *(const short8*)&hs[buf][l15][32 + quad * 8];
        acc[0] = __builtin_amdgcn_mfma_f32_16x16x32_bf16(a0, bf00, acc[0], 0, 0, 0);
        acc[0] = __builtin_amdgcn_mfma_f32_16x16x32_bf16(a1, bf01, acc[0], 0, 0, 0);
        acc[1] = __builtin_amdgcn_mfma_f32_16x16x32_bf16(a0, bf10, acc[1], 0, 0, 0);
        acc[1] = __builtin_amdgcn_mfma_f32_16x16x32_bf16(a1, bf11, acc[1], 0, 0, 0);
    }

    const float* bias = pj ? bk : bq;
    float scale = pj ? 1.0f : 0.125f;
    u16* outp = pj ? Kbf : Qbf;
    float bv0 = bias[nh + l15], bv1 = bias[nh + 16 + l15];
#pragma unroll
    for (int rr = 0; rr < 4; rr++) {
        size_t row = (size_t)b * SEQ + s0 + quad * 4 + rr;
        outp[row * HDIM + nh + l15]      = f2bf((acc[0][rr] + bv0) * scale);
        outp[row * HDIM + nh + 16 + l15] = f2bf((acc[1][rr] + bv1) * scale);
    }
}

// ---------------------------------------------------------------------------
// K2: column softmax stats (softmax over q axis): per-(b,k) m = max_q s, l = sum_q exp(s-m).
// grid (S/16, B) x 256 thr; wave w covers q in [w*512, w*512+512); LDS combine.
// ---------------------------------------------------------------------------
__global__ __launch_bounds__(256) void stats_kernel(
    const u16* __restrict__ Qbf, const u16* __restrict__ Kbf,
    float* __restrict__ mArr, float* __restrict__ lArr)
{
    __shared__ float sm[4][16], sl[4][16];
    int b = blockIdx.y;
    int k0 = blockIdx.x * 16;
    int t = threadIdx.x, lane = t & 63, w = t >> 6;
    int l15 = lane & 15, quad = lane >> 4;
    const u16* Qb = Qbf + (size_t)b * SEQ * HDIM;
    const u16* Kb = Kbf + (size_t)b * SEQ * HDIM;
    short8 kf0 = *(const short8*)(Kb + (size_t)(k0 + l15) * HDIM + quad * 8);
    short8 kf1 = *(const short8*)(Kb + (size_t)(k0 + l15) * HDIM + 32 + quad * 8);
    float m_run = -1e30f, l_run = 0.f;
    int qs = w * 512;
    for (int q0 = qs; q0 < qs + 512; q0 += 16) {
        short8 qf0 = *(const short8*)(Qb + (size_t)(q0 + l15) * HDIM + quad * 8);
        short8 qf1 = *(const short8*)(Qb + (size_t)(q0 + l15) * HDIM + 32 + quad * 8);
        f32x4 acc = {0.f, 0.f, 0.f, 0.f};
        acc = __builtin_amdgcn_mfma_f32_16x16x32_bf16(qf0, kf0, acc, 0, 0, 0);
        acc = __builtin_amdgcn_mfma_f32_16x16x32_bf16(qf1, kf1, acc, 0, 0, 0);
        float tm = fmaxf(fmaxf(acc[0], acc[1]), fmaxf(acc[2], acc[3]));
        tm = fmaxf(tm, __shfl_xor(tm, 16, 64));
        tm = fmaxf(tm, __shfl_xor(tm, 32, 64));
        float mn = fmaxf(m_run, tm);
        float p = __expf(acc[0] - mn) + __expf(acc[1] - mn)
                + __expf(acc[2] - mn) + __expf(acc[3] - mn);
        p += __shfl_xor(p, 16, 64);
        p += __shfl_xor(p, 32, 64);
        l_run = l_run * __expf(m_run - mn) + p;
        m_run = mn;
    }
    if (quad == 0) { sm[w][l15] = m_run; sl[w][l15] = l_run; }
    __syncthreads();
    if (t < 16) {
        float m = fmaxf(fmaxf(sm[0][t], sm[1][t]), fmaxf(sm[2][t], sm[3][t]));
        float l = sl[0][t] * __expf(sm[0][t] - m) + sl[1][t] * __expf(sm[1][t] - m)
                + sl[2][t] * __expf(sm[2][t] - m) + sl[3][t] * __expf(sm[3][t] - m);
        mArr[b * SEQ + k0 + t] = m;
        lArr[b * SEQ + k0 + t] = l;
    }
}

// ---------------------------------------------------------------------------
// K3: hT[b][e][s] = bf16(h[b][s][e] / l[b][s])  — transpose + fold softmax denom.
// ---------------------------------------------------------------------------
__global__ __launch_bounds__(256) void transpose_kernel(
    const float* __restrict__ h, const float* __restrict__ lArr, u16* __restrict__ hT)
{
    __shared__ float tile[64][65];
    int b  = blockIdx.z;
    int s0 = blockIdx.x * 64, e0 = blockIdx.y * 64;
    int t = threadIdx.x, c = t & 63, r4 = t >> 6;
    const float* hb = h + (size_t)b * SEQ * EMBED;
    for (int r = r4; r < 64; r += 4)
        tile[r][c] = hb[(size_t)(s0 + r) * EMBED + e0 + c];
    __syncthreads();
    float il = 1.0f / lArr[b * SEQ + s0 + c];   // this thread always writes s-col s0+c
    u16* hTb = hT + (size_t)b * EMBED * SEQ;
    for (int er = r4; er < 64; er += 4)
        hTb[(size_t)(e0 + er) * SEQ + s0 + c] = f2bf(tile[c][er] * il);
}

// ---------------------------------------------------------------------------
// K4: Wmat[b][q][k] = bf16( exp(s - m[k]) )  (1/l folded into hT)
// grid (S/64, S/64, B); 4 waves, wave w = q-subtile w*16, loops 4 k-subtiles.
// ---------------------------------------------------------------------------
__global__ __launch_bounds__(256) void weights_kernel(
    const u16* __restrict__ Qbf, const u16* __restrict__ Kbf,
    const float* __restrict__ mArr, u16* __restrict__ Wmat)
{
    int b = blockIdx.z;
    int q0 = blockIdx.x * 64, k0 = blockIdx.y * 64;
    int t = threadIdx.x, lane = t & 63, w = t >> 6;
    int l15 = lane & 15, quad = lane >> 4;
    const u16* Qb = Qbf + (size_t)b * SEQ * HDIM;
    const u16* Kb = Kbf + (size_t)b * SEQ * HDIM;
    int q = q0 + w * 16;
    short8 qf0 = *(const short8*)(Qb + (size_t)(q + l15) * HDIM + quad * 8);
    short8 qf1 = *(const short8*)(Qb + (size_t)(q + l15) * HDIM + 32 + quad * 8);
    u16* Wb = Wmat + (size_t)b * SEQ * SEQ;
#pragma unroll
    for (int kt = 0; kt < 4; kt++) {
        int k = k0 + kt * 16;
        short8 kf0 = *(const short8*)(Kb + (size_t)(k + l15) * HDIM + quad * 8);
        short8 kf1 = *(const short8*)(Kb + (size_t)(k + l15) * HDIM + 32 + quad * 8);
        f32x4 acc = {0.f, 0.f, 0.f, 0.f};
        acc = __builtin_amdgcn_mfma_f32_16x16x32_bf16(qf0, kf0, acc, 0, 0, 0);
        acc = __builtin_amdgcn_mfma_f32_16x16x32_bf16(qf1, kf1, acc, 0, 0, 0);
        float mv = mArr[b * SEQ + k + l15];
#pragma unroll
        for (int r = 0; r < 4; r++) {
            float wv = __expf(acc[r] - mv);
            Wb[(size_t)(q + quad * 4 + r) * SEQ + k + l15] = f2bf(wv);
        }
    }
}

// ---------------------------------------------------------------------------
// K5: out[b][q][e] = sum_k Wmat[b][q][k] * hT[b][e][k]
// 128x128 tile, BK=32, global_load_lds width-16, XOR-swizzled LDS (conflict-free):
// 16B-chunk (row, cb) lives at LDS chunk row*4 + (cb ^ ((row>>1)&3)).
// ---------------------------------------------------------------------------
__global__ __launch_bounds__(256) void out_gemm_kernel(
    const u16* __restrict__ Wmat, const u16* __restrict__ hT, float* __restrict__ out)
{
    __shared__ u16 As[128 * 32];  // [q][k] swizzled
    __shared__ u16 Bs[128 * 32];  // [e][k] swizzled
    int b = blockIdx.z;
    int q0 = blockIdx.x * 128, e0 = blockIdx.y * 128;
    int t = threadIdx.x, lane = t & 63, w = t >> 6;
    int l15 = lane & 15, quad = lane >> 4;
    const u16* Wb  = Wmat + (size_t)b * SEQ * SEQ;
    const u16* hTb = hT + (size_t)b * EMBED * SEQ;
    int wq = (w & 1) * 64, we = (w >> 1) * 64;

    f32x4 acc[4][4];
#pragma unroll
    for (int qi = 0; qi < 4; qi++)
#pragma unroll
        for (int ei = 0; ei < 4; ei++) acc[qi][ei] = (f32x4){0.f, 0.f, 0.f, 0.f};

    int srow    = (lane >> 2);                               // row within 16-row group
    int scol_l  = (lane & 3) * 8;                            // LDS chunk (dest = base+lane*16)
    int scol_g  = (((lane & 3) ^ ((lane >> 3) & 3)) * 8);    // swizzled global source chunk
    int sw      = (quad ^ ((l15 >> 1) & 3)) * 8;             // swizzled frag-read chunk

    for (int k0 = 0; k0 < SEQ; k0 += 32) {
        __syncthreads();
#pragma unroll
        for (int ld = 0; ld < 2; ld++) {
            int row = w * 32 + ld * 16 + srow;
            gload_lds16(Wb  + (size_t)(q0 + row) * SEQ + k0 + scol_g, As + row * 32 + scol_l);
            gload_lds16(hTb + (size_t)(e0 + row) * SEQ + k0 + scol_g, Bs + row * 32 + scol_l);
        }
        __syncthreads();  // drains vmcnt (global_load_lds) before frag reads

        short8 af[4], bfr[4];
#pragma unroll
        for (int i = 0; i < 4; i++) {
            af[i]  = *(const short8*)(As + (wq + i * 16 + l15) * 32 + sw);
            bfr[i] = *(const short8*)(Bs + (we + i * 16 + l15) * 32 + sw);
        }
#pragma unroll
        for (int qi = 0; qi < 4; qi++)
#pragma unroll
            for (int ei = 0; ei < 4; ei++)
                acc[qi][ei] = __builtin_amdgcn_mfma_f32_16x16x32_bf16(
                    af[qi], bfr[ei], acc[qi][ei], 0, 0, 0);
    }

    float* outb = out + (size_t)b * SEQ * EMBED;
#pragma unroll
    for (int qi = 0; qi < 4; qi++)
#pragma unroll
        for (int ei = 0; ei < 4; ei++)
#pragma unroll
            for (int r = 0; r < 4; r++)
                outb[(size_t)(q0 + wq + qi * 16 + quad * 4 + r) * EMBED
                     + e0 + we + ei * 16 + l15] = acc[qi][ei][r];
}

// ---------------------------------------------------------------------------
extern "C" void kernel_launch(void* const* d_in, const int* in_sizes, int n_in,
                              void* d_out, int out_size, void* d_ws, size_t ws_size,
                              hipStream_t stream) {
    (void)in_sizes; (void)n_in; (void)out_size; (void)ws_size;
    const float* h  = (const float*)d_in[0];
    const float* Wq = (const float*)d_in[1];
    const float* bq = (const float*)d_in[2];
    const float* Wk = (const float*)d_in[3];
    const float* bk = (const float*)d_in[4];
    // d_in[5], d_in[6] (Wv, bv) are dead in the reference.
    float* out = (float*)d_out;

    char* ws = (char*)d_ws;
    u16*   Qbf  = (u16*)(ws);                                  // 1 MB
    u16*   Kbf  = (u16*)(ws + (1ull << 20));                   // 1 MB
    u16*   hT   = (u16*)(ws + (2ull << 20));                   // 16 MB
    float* mArr = (float*)(ws + (18ull << 20));                // 32 KB
    float* lArr = (float*)(ws + (18ull << 20) + (64ull << 10));// 32 KB
    u16*   WqT  = (u16*)(ws + (18ull << 20) + (128ull << 10)); // 128 KB
    u16*   WkT  = (u16*)(ws + (18ull << 20) + (256ull << 10)); // 128 KB
    u16*   Wmat = (u16*)(ws + (19ull << 20));                  // 32 MB (total ~51 MB)

    hipLaunchKernelGGL(wt_kernel, dim3(16, 2), dim3(256), 0, stream, Wq, Wk, WqT, WkT);
    hipLaunchKernelGGL(proj_kernel, dim3(512), dim3(256), 0, stream,
                       h, WqT, WkT, bq, bk, Qbf, Kbf);
    hipLaunchKernelGGL(stats_kernel, dim3(128, 4), dim3(256), 0, stream,
                       Qbf, Kbf, mArr, lArr);
    hipLaunchKernelGGL(transpose_kernel, dim3(32, 16, 4), dim3(256), 0, stream,
                       h, lArr, hT);
    hipLaunchKernelGGL(weights_kernel, dim3(32, 32, 4), dim3(256), 0, stream,
                       Qbf, Kbf, mArr, Wmat);
    hipLaunchKernelGGL(out_gemm_kernel, dim3(16, 8, 4), dim3(256), 0, stream,
                       Wmat, hT, out);
}